// Round 14
// baseline (757.671 us; speedup 1.0000x reference)
//
#include <hip/hip_runtime.h>
#include <hip/hip_bf16.h>

typedef __attribute__((ext_vector_type(4))) float f32x4;
typedef __attribute__((ext_vector_type(8))) short bf16x8;
typedef __attribute__((ext_vector_type(2))) unsigned short u16x2;
typedef __attribute__((ext_vector_type(4))) unsigned short u16x4;
typedef __attribute__((ext_vector_type(8))) unsigned short u16x8;

#define S_LEN 2048
#define BATCH 2
#define DMODEL 512
#define NHEAD 8
#define HDIM 64
#define MROWS 4096   // S*B
#define LAYERS 6

#define MFMA16(a, b, c) __builtin_amdgcn_mfma_f32_16x16x32_bf16((a), (b), (c), 0, 0, 0)

// async global->LDS DMA, 16B per lane (lds dst = wave-uniform base + lane*16)
#define GLDS16(g, l)                                                         \
    __builtin_amdgcn_global_load_lds(                                        \
        (const __attribute__((address_space(1))) unsigned int*)(g),          \
        (__attribute__((address_space(3))) unsigned int*)(l), 16, 0, 0)

__device__ __forceinline__ float bf2f(unsigned short u) {
    return __uint_as_float(((unsigned)u) << 16);
}
__device__ __forceinline__ unsigned short f2bf(float f) {
    union { float f; unsigned u; } v; v.f = f;
    unsigned r = v.u + 0x7FFF + ((v.u >> 16) & 1);   // RNE
    return (unsigned short)(r >> 16);
}
__device__ __forceinline__ bf16x8 load8(const unsigned short* p) {
    return *reinterpret_cast<const bf16x8*>(p);
}

// ---------------- f32 -> bf16 bulk convert ----------------
__global__ __launch_bounds__(256) void f2bf_kernel(
    const float* __restrict__ src, unsigned short* __restrict__ dst, int n8)
{
    int i = blockIdx.x * 256 + threadIdx.x;
    if (i >= n8) return;
    f32x4 a = *reinterpret_cast<const f32x4*>(src + (size_t)i * 8);
    f32x4 b = *reinterpret_cast<const f32x4*>(src + (size_t)i * 8 + 4);
    u16x8 o;
#pragma unroll
    for (int j = 0; j < 4; ++j) { o[j] = f2bf(a[j]); o[4 + j] = f2bf(b[j]); }
    *reinterpret_cast<u16x8*>(dst + (size_t)i * 8) = o;
}

// ---------------- embedding + sinusoidal PE (double-precision PE to match np) ----------------
__global__ __launch_bounds__(256) void embed_pe_kernel(
    const int* __restrict__ seq, const float* __restrict__ emb,
    float* __restrict__ x, unsigned short* __restrict__ x16)
{
    const int r = blockIdx.x;       // 0..4095  (r = s*B + b)
    const int j = threadIdx.x;      // pair index: cols 2j, 2j+1
    const int s = r >> 1, b = r & 1;
    const int tok = seq[b * S_LEN + s];
    const float e0 = emb[(size_t)tok * DMODEL + 2 * j];
    const float e1 = emb[(size_t)tok * DMODEL + 2 * j + 1];
    const double c = -9.210340371976184 / 512.0;   // -ln(10000)/D
    double dv = exp((double)(2 * j) * c);
    double arg = (double)s * dv;
    const float v0 = e0 + (float)sin(arg);
    const float v1 = e1 + (float)cos(arg);
    x[(size_t)r * DMODEL + 2 * j]     = v0;
    x[(size_t)r * DMODEL + 2 * j + 1] = v1;
    u16x2 o; o[0] = f2bf(v0); o[1] = f2bf(v1);
    *reinterpret_cast<u16x2*>(x16 + (size_t)r * DMODEL + 2 * j) = o;
}

// ---------------- MFMA GEMM: C[M=4096,N] = A16[M,K] * W16[N,K]^T + bias ----------------
// BM x 64 tile, BK=64, 256 thr = 4 waves (2x2). global_load_lds staging with
// pre-swizzled SOURCE addresses (LDS contents identical to prior swizzled layout).
// qkvsplit: cols [0,1024) -> Cb stride 1024 (q scaled 0.125 for col<512);
//           cols [1024,1536) -> vT (block-transposed, bit-permuted V buffer).
template<int BM>
__global__ __launch_bounds__(256) void gemm_mfma_kernel(
    const unsigned short* __restrict__ A, const unsigned short* __restrict__ W,
    const float* __restrict__ bias,
    float* __restrict__ Cf, unsigned short* __restrict__ Cb,
    unsigned short* __restrict__ vT,
    int N, int K, int relu, int qkvsplit)
{
    constexpr int MF = BM / 32;     // m-frags per wave; also A-DMA instrs per wave
    __shared__ __align__(16) unsigned short As[BM * 64];
    __shared__ __align__(16) unsigned short Bs[64 * 64];
    const int tid = threadIdx.x;
    const int w = tid >> 6, lane = tid & 63, l15 = lane & 15, hi = lane >> 4;
    const int wm = w >> 1, wn = w & 1;
    const int n0 = blockIdx.x * 64, m0 = blockIdx.y * BM;
    const int lrow = lane >> 3;     // row within 8-row DMA group
    const int lslot = lane & 7;     // granule slot

    // per-lane pre-swizzled source offsets (elements); dst = linear As/Bs
    size_t preA[MF]; int ldsA[MF];
#pragma unroll
    for (int jj = 0; jj < MF; ++jj) {
        const int r0 = 32 * jj + 8 * w;
        const int r = r0 + lrow;
        const int sw = (r >> 1) & 7;
        preA[jj] = (size_t)(m0 + r) * K + ((lslot ^ sw) * 8);
        ldsA[jj] = r0 * 64;
    }
    size_t preB[2]; int ldsB[2];
#pragma unroll
    for (int jj = 0; jj < 2; ++jj) {
        const int r0 = 32 * jj + 8 * w;
        const int r = r0 + lrow;
        const int sw = (r >> 1) & 7;
        int nn = n0 + r; if (nn > N - 1) nn = N - 1;   // clamp: finite garbage, unsaved
        preB[jj] = (size_t)nn * K + ((lslot ^ sw) * 8);
        ldsB[jj] = r0 * 64;
    }

    f32x4 acc[MF][2];
#pragma unroll
    for (int mf = 0; mf < MF; ++mf)
#pragma unroll
        for (int nf = 0; nf < 2; ++nf) acc[mf][nf] = f32x4{0.f, 0.f, 0.f, 0.f};

    for (int k0 = 0; k0 < K; k0 += 64) {
        __syncthreads();
#pragma unroll
        for (int jj = 0; jj < MF; ++jj) GLDS16(A + preA[jj] + k0, As + ldsA[jj]);
#pragma unroll
        for (int jj = 0; jj < 2; ++jj)  GLDS16(W + preB[jj] + k0, Bs + ldsB[jj]);
        __syncthreads();

        bf16x8 af[MF][2], bfr[2][2];
#pragma unroll
        for (int mf = 0; mf < MF; ++mf) {
            const int r = wm * (BM / 2) + mf * 16 + l15;
            const int sw = (r >> 1) & 7;
            const unsigned short* base = As + r * 64;
            af[mf][0] = *reinterpret_cast<const bf16x8*>(base + ((hi ^ sw) * 8));
            af[mf][1] = *reinterpret_cast<const bf16x8*>(base + (((hi + 4) ^ sw) * 8));
        }
#pragma unroll
        for (int nf = 0; nf < 2; ++nf) {
            const int r = wn * 32 + nf * 16 + l15;
            const int sw = (r >> 1) & 7;
            const unsigned short* base = Bs + r * 64;
            bfr[nf][0] = *reinterpret_cast<const bf16x8*>(base + ((hi ^ sw) * 8));
            bfr[nf][1] = *reinterpret_cast<const bf16x8*>(base + (((hi + 4) ^ sw) * 8));
        }
#pragma unroll
        for (int mf = 0; mf < MF; ++mf)
#pragma unroll
            for (int nf = 0; nf < 2; ++nf) {
                acc[mf][nf] = MFMA16(af[mf][0], bfr[nf][0], acc[mf][nf]);
                acc[mf][nf] = MFMA16(af[mf][1], bfr[nf][1], acc[mf][nf]);
            }
    }

    // ---- epilogue: bias (+relu) -> f32 / bf16 / split qk+vT ----
#pragma unroll
    for (int nf = 0; nf < 2; ++nf) {
        const int col = n0 + wn * 32 + nf * 16 + l15;
        const bool okc = col < N;
        const float bv = okc ? bias[col] : 0.f;
#pragma unroll
        for (int mf = 0; mf < MF; ++mf) {
            const int rbase = m0 + wm * (BM / 2) + mf * 16 + hi * 4;
#pragma unroll
            for (int rg = 0; rg < 4; ++rg) {
                float v = acc[mf][nf][rg] + bv;
                if (relu) v = fmaxf(v, 0.f);
                if (okc) {
                    const int row = rbase + rg;
                    if (qkvsplit) {
                        if (col < 1024) {
                            if (col < 512) v *= 0.125f;
                            Cb[(size_t)row * 1024 + col] = f2bf(v);
                        } else {
                            const int h = (col - 1024) >> 6, d = (col - 1024) & 63;
                            const int s = row >> 1, bb = row & 1;
                            const int kt = s >> 6, kin = s & 63;
                            const int pos = (kin & 3) | (((kin >> 4) & 1) << 2)
                                          | (((kin >> 2) & 3) << 3) | (kin & 32);
                            vT[((((size_t)(bb * 8 + h) * 32 + kt) * 64 + d) << 6) + pos] = f2bf(v);
                        }
                    } else {
                        const size_t idx = (size_t)row * N + col;
                        if (Cb) Cb[idx] = f2bf(v);
                        else    Cf[idx] = v;
                    }
                }
            }
        }
    }
}

// ---------------- MFMA flash attention, KV-split (512-key chunks) ----------------
// qk16: [r=s*B+b][1024] bf16 (q pre-scaled | k). vT16: [bh][kt][d][pos(k)] bf16.
// er16: [2048][64] bf16. srel[q,k] = q.er[2047-q+k], k<=q.
// Grid (16 bh fast, 80 tasks slow). Task bx -> (qb, chunk c):
//   bx<32: qb=31-bx, c=0; bx<56: qb=31-(bx-32), c=1; bx<72: qb=31-(bx-56), c=2;
//   else:  qb=31-(bx-72), c=3.   Chunk = 512 keys (<=8 tiles of 64).
__global__ __launch_bounds__(256, 2) void attn_mfma_kernel(
    const unsigned short* __restrict__ qk16, const unsigned short* __restrict__ vT16,
    const unsigned short* __restrict__ er16,
    unsigned short* __restrict__ part16, float* __restrict__ mlbuf)
{
    __shared__ __align__(16) unsigned short K_s[64 * 64];     // [k][d] granule-swizzled
    __shared__ __align__(16) unsigned short V_T[64 * 64];     // [d][pos(k)] granule-swizzled
    __shared__ __align__(16) unsigned short Er_s[64 * 64];    // er rows fb..fb+63, swizzled
    __shared__ __align__(16) unsigned short E_w[4 * 16 * 196];// per-wave [q=16][192+4]

    const int tid  = threadIdx.x;
    const int w    = tid >> 6;
    const int lane = tid & 63;
    const int l15  = lane & 15;
    const int hi   = lane >> 4;
    const int bx   = blockIdx.y;        // task 0..79 (slow axis)
    const int bh   = blockIdx.x;        // 0..15
    const int b    = bh >> 3, hh = bh & 7;
    const int sk   = lane;              // K staging k-row
    const int dg0  = w;                 // K staging d-granules w, w+4
    const int dv0  = 16 * w + (lane >> 3);      // V staging d-rows dv0, dv0+8
    const int gv   = lane & 7;                  // V staging granule

    int qb, c;
    if (bx < 32)      { qb = 31 - bx;        c = 0; }
    else if (bx < 56) { qb = 31 - (bx - 32); c = 1; }
    else if (bx < 72) { qb = 31 - (bx - 56); c = 2; }
    else              { qb = 31 - (bx - 72); c = 3; }
    const int pidx = bh * 80 + bx;
    const int q0   = qb * 64;
    const int k0s  = c * 512;
    const int ntl  = min(qb + 1 - c * 8, 8);     // tiles in this chunk (1..8)
    const int qg   = q0 + 16 * w + l15;

    const unsigned short* qptr = qk16 + ((size_t)qg * BATCH + b) * 1024 + hh * HDIM;
    bf16x8 qf0 = load8(qptr + hi * 8);
    bf16x8 qf1 = load8(qptr + 32 + hi * 8);

    unsigned short* ewp = E_w + (w * 16 + l15) * 196;
    const int E0  = 1984 - q0 + k0s;
    const int E0m = E0 % 192;

    // ---- prologue: QE rows [E0, E0+127] (direct global, once per block) ----
#pragma unroll 2
    for (int mf = 0; mf < 8; ++mf) {
        int e = E0 + mf * 16 + l15;
        int ec = e > 2047 ? 2047 : e;    // clamped rows are causally masked later
        bf16x8 a0 = load8(er16 + (size_t)ec * 64 + hi * 8);
        bf16x8 a1 = load8(er16 + (size_t)ec * 64 + 32 + hi * 8);
        f32x4 acc = {0.f, 0.f, 0.f, 0.f};
        acc = MFMA16(a0, qf0, acc);
        acc = MFMA16(a1, qf1, acc);
        int col = E0m + mf * 16 + 4 * hi;
        if (col >= 192) col -= 192;
        u16x4 ew;
#pragma unroll
        for (int r = 0; r < 4; ++r) ew[r] = f2bf(acc[r]);
        *reinterpret_cast<u16x4*>(ewp + col) = ew;
    }

    float m = -INFINITY, lsum = 0.f;
    f32x4 acc_o[4];
#pragma unroll
    for (int mf = 0; mf < 4; ++mf) acc_o[mf] = f32x4{0.f, 0.f, 0.f, 0.f};

    int col0t = (2047 - qg + k0s) % 192;

    // ---- prefetch tile 0 K/V into regs (+ er rows for tile 0's QE-next) ----
    bf16x8 kpr0, kpr1, vpr0, vpr1, epr0, epr1;
    {
        const unsigned short* krow = qk16 + ((size_t)(k0s + sk) * BATCH + b) * 1024 + 512 + hh * HDIM;
        kpr0 = load8(krow + dg0 * 8);       kpr1 = load8(krow + (dg0 + 4) * 8);
        const unsigned short* vbase = vT16 + (((size_t)bh * 32 + (k0s >> 6)) * 64) * 64;
        vpr0 = load8(vbase + dv0 * 64 + gv * 8);
        vpr1 = load8(vbase + (dv0 + 8) * 64 + gv * 8);
    }
    if (ntl > 1) {
        int e = E0 + 128 + sk;
        int ec = e > 2047 ? 2047 : e;
        epr0 = load8(er16 + (size_t)ec * 64 + dg0 * 8);
        epr1 = load8(er16 + (size_t)ec * 64 + (dg0 + 4) * 8);
    }

    for (int t = 0; t < ntl; ++t) {
        const int k0 = k0s + t * 64;
        const bool doE = (t + 1 < ntl);
        __syncthreads();
        // ---- write prefetched K, V^T, Er (all swizzled b128) ----
        *reinterpret_cast<bf16x8*>(K_s + sk * 64 + ((dg0 ^ (sk & 7)) * 8)) = kpr0;
        *reinterpret_cast<bf16x8*>(K_s + sk * 64 + (((dg0 + 4) ^ (sk & 7)) * 8)) = kpr1;
        *reinterpret_cast<bf16x8*>(V_T + dv0 * 64 + ((gv ^ (dv0 & 7)) * 8)) = vpr0;
        *reinterpret_cast<bf16x8*>(V_T + (dv0 + 8) * 64 + ((gv ^ (dv0 & 7)) * 8)) = vpr1;
        if (doE) {
            *reinterpret_cast<bf16x8*>(Er_s + sk * 64 + ((dg0 ^ (sk & 7)) * 8)) = epr0;
            *reinterpret_cast<bf16x8*>(Er_s + sk * 64 + (((dg0 + 4) ^ (sk & 7)) * 8)) = epr1;
        }
        // ---- prefetch next tile's K/V (+ er rows for next tile's QE) ----
        if (t + 1 < ntl) {
            const unsigned short* krow = qk16 + ((size_t)(k0 + 64 + sk) * BATCH + b) * 1024 + 512 + hh * HDIM;
            kpr0 = load8(krow + dg0 * 8);       kpr1 = load8(krow + (dg0 + 4) * 8);
            const unsigned short* vbase = vT16 + (((size_t)bh * 32 + ((k0 + 64) >> 6)) * 64) * 64;
            vpr0 = load8(vbase + dv0 * 64 + gv * 8);
            vpr1 = load8(vbase + (dv0 + 8) * 64 + gv * 8);
            if (t + 2 < ntl) {
                int e = E0 + 128 + 64 * (t + 1) + sk;
                int ec = e > 2047 ? 2047 : e;
                epr0 = load8(er16 + (size_t)ec * 64 + dg0 * 8);
                epr1 = load8(er16 + (size_t)ec * 64 + (dg0 + 4) * 8);
            }
        }
        __syncthreads();

        // ---- QK: S^T[k][q] = K x Q ----
        f32x4 sacc[4];
#pragma unroll
        for (int f = 0; f < 4; ++f) {
            const int row = l15 + 16 * f;
            bf16x8 ka0 = *reinterpret_cast<const bf16x8*>(K_s + row * 64 + (((0 + hi) ^ (l15 & 7)) * 8));
            bf16x8 ka1 = *reinterpret_cast<const bf16x8*>(K_s + row * 64 + (((4 + hi) ^ (l15 & 7)) * 8));
            f32x4 z = {0.f, 0.f, 0.f, 0.f};
            z = MFMA16(ka0, qf0, z);
            sacc[f] = MFMA16(ka1, qf1, z);
        }

        // ---- QE for next tile: A-frags from Er_s ----
        if (doE) {
            const int fbm = (E0 + 128 + 64 * t) % 192;
#pragma unroll
            for (int mf = 0; mf < 4; ++mf) {
                const int rr = l15 + 16 * mf;
                bf16x8 a0 = *reinterpret_cast<const bf16x8*>(Er_s + rr * 64 + ((hi ^ (l15 & 7)) * 8));
                bf16x8 a1 = *reinterpret_cast<const bf16x8*>(Er_s + rr * 64 + (((hi + 4) ^ (l15 & 7)) * 8));
                f32x4 acc = {0.f, 0.f, 0.f, 0.f};
                acc = MFMA16(a0, qf0, acc);
                acc = MFMA16(a1, qf1, acc);
                int col = fbm + mf * 16 + 4 * hi;
                u16x4 ew;
#pragma unroll
                for (int r = 0; r < 4; ++r) ew[r] = f2bf(acc[r]);
                *reinterpret_cast<u16x4*>(ewp + col) = ew;
            }
        }

        // ---- gather QE diagonal + causal mask + online softmax (in-place) ----
        float mt = -INFINITY;
#pragma unroll
        for (int f = 0; f < 4; ++f) {
#pragma unroll
            for (int r = 0; r < 4; ++r) {
                const int kk = 16 * f + 4 * hi + r;
                int col = col0t + kk;
                if (col >= 192) col -= 192;
                float sv = sacc[f][r] + bf2f(ewp[col]);
                if (k0 + kk > qg) sv = -1e9f;
                sacc[f][r] = sv;
                mt = fmaxf(mt, sv);
            }
        }
        mt = fmaxf(mt, __shfl_xor(mt, 16));
        mt = fmaxf(mt, __shfl_xor(mt, 32));
        const float mn = fmaxf(m, mt);
        const float corr = __expf(m - mn);
        float ps = 0.f;
#pragma unroll
        for (int f = 0; f < 4; ++f)
#pragma unroll
            for (int r = 0; r < 4; ++r) {
                const float e = __expf(sacc[f][r] - mn);
                sacc[f][r] = e; ps += e;
            }
        ps += __shfl_xor(ps, 16);
        ps += __shfl_xor(ps, 32);
        lsum = lsum * corr + ps;
        m = mn;

        // ---- pack P to bf16 B-frags ----
        bf16x8 pf0, pf1;
#pragma unroll
        for (int j = 0; j < 8; ++j) {
            pf0[j] = (short)f2bf(sacc[j >> 2][j & 3]);
            pf1[j] = (short)f2bf(sacc[(j >> 2) + 2][j & 3]);
        }

        // ---- rescale + PV: ctx^T = V^T x P (direct b128 A-frags) ----
#pragma unroll
        for (int mf = 0; mf < 4; ++mf) {
            f32x4 a = acc_o[mf];
            a[0] *= corr; a[1] *= corr; a[2] *= corr; a[3] *= corr;
            const unsigned short* vrow = V_T + (l15 + 16 * mf) * 64;
            const int sw = l15 & 7;
            bf16x8 vf0 = *reinterpret_cast<const bf16x8*>(vrow + ((hi ^ sw) * 8));
            bf16x8 vf1 = *reinterpret_cast<const bf16x8*>(vrow + (((4 + hi) ^ sw) * 8));
            a = MFMA16(vf0, pf0, a);
            a = MFMA16(vf1, pf1, a);
            acc_o[mf] = a;
        }

        col0t += 64;
        if (col0t >= 192) col0t -= 192;
    }

    // ---- epilogue: write un-normalized partials ----
    unsigned short* pa = part16 + ((size_t)pidx * 64 + 16 * w + l15) * 64;
#pragma unroll
    for (int mf = 0; mf < 4; ++mf) {
        u16x4 o;
#pragma unroll
        for (int r = 0; r < 4; ++r) o[r] = f2bf(acc_o[mf][r]);
        *reinterpret_cast<u16x4*>(pa + 16 * mf + 4 * hi) = o;
    }
    if (hi == 0) {
        float* ml = mlbuf + ((size_t)pidx * 64 + 16 * w + l15) * 2;
        ml[0] = m; ml[1] = lsum;
    }
}

// ---------------- combine partials -> ctx16 (up to 4 chunks, online merge) ----------------
__global__ __launch_bounds__(256) void attn_combine_kernel(
    const unsigned short* __restrict__ part16, const float* __restrict__ mlbuf,
    unsigned short* __restrict__ ctx16)
{
    const int flat = blockIdx.x * 256 + threadIdx.x;
    const int qi = flat >> 3, dg = flat & 7;
    const int bh = qi >> 11, ql = qi & 2047;
    const int b = bh >> 3, hh = bh & 7;
    const int qb = ql >> 6, rl = ql & 63;

    const int nch = (qb >> 3) + 1;              // 1..4 chunks
    float mr = -1e30f, lr = 0.f;
    float o[8];
#pragma unroll
    for (int j = 0; j < 8; ++j) o[j] = 0.f;

    for (int cc = 0; cc < nch; ++cc) {
        const int cb = (cc == 0) ? 0 : (cc == 1) ? 32 : (cc == 2) ? 56 : 72;
        const int idx = bh * 80 + cb + (31 - qb);
        const float* ml = mlbuf + ((size_t)idx * 64 + rl) * 2;
        const float mc = ml[0], lc = ml[1];
        u16x8 a = *reinterpret_cast<const u16x8*>(part16 + ((size_t)idx * 64 + rl) * 64 + dg * 8);
        const float mn = fmaxf(mr, mc);
        const float w0 = __expf(mr - mn), w1 = __expf(mc - mn);
#pragma unroll
        for (int j = 0; j < 8; ++j) o[j] = o[j] * w0 + bf2f(a[j]) * w1;
        lr = lr * w0 + lc * w1;
        mr = mn;
    }
    const float inv = 1.f / lr;
    u16x8 res;
#pragma unroll
    for (int j = 0; j < 8; ++j) res[j] = f2bf(o[j] * inv);
    *reinterpret_cast<u16x8*>(ctx16 + ((size_t)ql * BATCH + b) * DMODEL + hh * HDIM + dg * 8) = res;
}

// ---------------- LayerNorm (fused residual add), writes f32 + bf16 ----------------
__global__ __launch_bounds__(256) void ln_kernel(
    const float* __restrict__ xin, const float* __restrict__ res,
    const float* __restrict__ gg, const float* __restrict__ bb,
    float* __restrict__ xout, unsigned short* __restrict__ x16out, int has_res)
{
    const int w = threadIdx.x >> 6, lane = threadIdx.x & 63;
    const int row = blockIdx.x * 4 + w;
    const float* xp = xin + (size_t)row * DMODEL + lane * 8;
    f32x4 v0 = *reinterpret_cast<const f32x4*>(xp);
    f32x4 v1 = *reinterpret_cast<const f32x4*>(xp + 4);
    if (has_res) {
        const float* rp = res + (size_t)row * DMODEL + lane * 8;
        v0 += *reinterpret_cast<const f32x4*>(rp);
        v1 += *reinterpret_cast<const f32x4*>(rp + 4);
    }
    float sum = 0.f, ssq = 0.f;
#pragma unroll
    for (int c2 = 0; c2 < 4; ++c2) {
        sum += v0[c2] + v1[c2];
        ssq += v0[c2] * v0[c2] + v1[c2] * v1[c2];
    }
#pragma unroll
    for (int off = 32; off > 0; off >>= 1) {
        sum += __shfl_xor(sum, off);
        ssq += __shfl_xor(ssq, off);
    }
    const float mu = sum * (1.f / 512.f);
    const float var = ssq * (1.f / 512.f) - mu * mu;
    const float rstd = rsqrtf(var + 1e-5f);
    f32x4 g0 = *reinterpret_cast<const f32x4*>(gg + lane * 8);
    f32x4 g1 = *reinterpret_cast<const f32x4*>(gg + lane * 8 + 4);
    f32x4 b0 = *reinterpret_cast<const f32x4*>(bb + lane * 8);
    f32x4 b1 = *reinterpret_cast<const f32x4*>(bb + lane * 8 + 4);
    f32x4 o0, o1;
    u16x8 h;
#pragma unroll
    for (int c2 = 0; c2 < 4; ++c2) {
        o0[c2] = (v0[c2] - mu) * rstd * g0[c2] + b0[c2];
        o1[c2] = (v1[c2] - mu) * rstd * g1[c2] + b1[c2];
        h[c2] = f2bf(o0[c2]); h[4 + c2] = f2bf(o1[c2]);
    }
    float* op = xout + (size_t)row * DMODEL + lane * 8;
    *reinterpret_cast<f32x4*>(op)     = o0;
    *reinterpret_cast<f32x4*>(op + 4) = o1;
    *reinterpret_cast<u16x8*>(x16out + (size_t)row * DMODEL + lane * 8) = h;
}

// ---------------- host launch ----------------
extern "C" void kernel_launch(void* const* d_in, const int* in_sizes, int n_in,
                              void* d_out, int out_size, void* d_ws, size_t ws_size,
                              hipStream_t stream)
{
    const int*   seq  = (const int*)d_in[0];
    const float* emb  = (const float*)d_in[1];
    const float* ipw  = (const float*)d_in[2];
    const float* ipb  = (const float*)d_in[3];
    const float* opw  = (const float*)d_in[4];
    const float* opb  = (const float*)d_in[5];
    const float* er   = (const float*)d_in[6];
    const float* l1w  = (const float*)d_in[7];
    const float* l1b  = (const float*)d_in[8];
    const float* l2w  = (const float*)d_in[9];
    const float* l2b  = (const float*)d_in[10];
    const float* ln1g = (const float*)d_in[11];
    const float* ln1b = (const float*)d_in[12];
    const float* ln2g = (const float*)d_in[13];
    const float* ln2b = (const float*)d_in[14];
    const float* flng = (const float*)d_in[15];
    const float* flnb = (const float*)d_in[16];
    const float* ww   = (const float*)d_in[17];
    const float* wb   = (const float*)d_in[18];
    float* out = (float*)d_out;

    float* xf  = (float*)d_ws;                               // [4096][512] f32
    float* tmp = xf + (size_t)MROWS * DMODEL;                // [4096][512] f32
    unsigned short* x16   = (unsigned short*)(tmp + (size_t)MROWS * DMODEL);  // [4096][512]
    unsigned short* qk16  = x16  + (size_t)MROWS * DMODEL;   // [4096][1024] (h16 aliases)
    unsigned short* ctx16 = qk16 + (size_t)MROWS * 1024;     // [4096][512]
    unsigned short* er16  = ctx16 + (size_t)MROWS * DMODEL;  // [6][2048][64]
    unsigned short* vT16  = er16 + (size_t)LAYERS * S_LEN * HDIM;  // [16][32][64][64]
    unsigned short* w16   = vT16 + (size_t)16 * 32 * 64 * 64;
    unsigned short* h16   = qk16;                            // alias (disjoint lifetime)
    // attention partials overlay tmp+x16 (both dead during attn -> combine):
    unsigned short* part16 = (unsigned short*)tmp;
    float* mlbuf = (float*)(part16 + (size_t)1280 * 64 * 64);

    unsigned short* ipw16 = w16;                             // 6*1536*512
    unsigned short* opw16 = ipw16 + (size_t)LAYERS * 1536 * DMODEL;
    unsigned short* l1w16 = opw16 + (size_t)LAYERS * DMODEL * DMODEL;
    unsigned short* l2w16 = l1w16 + (size_t)LAYERS * 1024 * DMODEL;
    unsigned short* ww16  = l2w16 + (size_t)LAYERS * DMODEL * 1024;

    // ---- weight + er conversion (once per launch) ----
    {
        int n8;
        n8 = LAYERS * 1536 * DMODEL / 8; f2bf_kernel<<<(n8 + 255) / 256, 256, 0, stream>>>(ipw, ipw16, n8);
        n8 = LAYERS * DMODEL * DMODEL / 8; f2bf_kernel<<<(n8 + 255) / 256, 256, 0, stream>>>(opw, opw16, n8);
        n8 = LAYERS * 1024 * DMODEL / 8; f2bf_kernel<<<(n8 + 255) / 256, 256, 0, stream>>>(l1w, l1w16, n8);
        n8 = LAYERS * DMODEL * 1024 / 8; f2bf_kernel<<<(n8 + 255) / 256, 256, 0, stream>>>(l2w, l2w16, n8);
        n8 = 267 * DMODEL / 8;           f2bf_kernel<<<(n8 + 255) / 256, 256, 0, stream>>>(ww, ww16, n8);
        n8 = LAYERS * S_LEN * HDIM / 8;  f2bf_kernel<<<(n8 + 255) / 256, 256, 0, stream>>>(er, er16, n8);
    }

    embed_pe_kernel<<<MROWS, 256, 0, stream>>>(seq, emb, xf, x16);

    for (int i = 0; i < LAYERS; ++i) {
        gemm_mfma_kernel<128><<<dim3(24, 32), 256, 0, stream>>>(
            x16, ipw16 + (size_t)i * 1536 * DMODEL, ipb + (size_t)i * 1536,
            nullptr, qk16, vT16, 1536, DMODEL, 0, 1);
        attn_mfma_kernel<<<dim3(BATCH * NHEAD, 80), 256, 0, stream>>>(
            qk16, vT16, er16 + (size_t)i * S_LEN * HDIM, part16, mlbuf);
        attn_combine_kernel<<<1024, 256, 0, stream>>>(part16, mlbuf, ctx16);
        gemm_mfma_kernel<64><<<dim3(8, 64), 256, 0, stream>>>(
            ctx16, opw16 + (size_t)i * DMODEL * DMODEL, opb + (size_t)i * DMODEL,
            tmp, nullptr, nullptr, DMODEL, DMODEL, 0, 0);
        ln_kernel<<<MROWS / 4, 256, 0, stream>>>(
            xf, tmp, ln1g + (size_t)i * DMODEL, ln1b + (size_t)i * DMODEL, xf, x16, 1);
        gemm_mfma_kernel<128><<<dim3(16, 32), 256, 0, stream>>>(
            x16, l1w16 + (size_t)i * 1024 * DMODEL, l1b + (size_t)i * 1024,
            nullptr, h16, nullptr, 1024, DMODEL, 1, 0);
        gemm_mfma_kernel<64><<<dim3(8, 64), 256, 0, stream>>>(
            h16, l2w16 + (size_t)i * DMODEL * 1024, l2b + (size_t)i * DMODEL,
            tmp, nullptr, nullptr, DMODEL, 1024, 0, 0);
        ln_kernel<<<MROWS / 4, 256, 0, stream>>>(
            xf, tmp, ln2g + (size_t)i * DMODEL, ln2b + (size_t)i * DMODEL, xf, x16, 1);
    }

    ln_kernel<<<MROWS / 4, 256, 0, stream>>>(xf, nullptr, flng, flnb, xf, x16, 0);
    gemm_mfma_kernel<64><<<dim3(5, 64), 256, 0, stream>>>(
        x16, ww16, wb, out, nullptr, nullptr, 267, DMODEL, 0, 0);
}

// Round 15
// 715.373 us; speedup vs baseline: 1.0591x; 1.0591x over previous
//
#include <hip/hip_runtime.h>
#include <hip/hip_bf16.h>

typedef __attribute__((ext_vector_type(4))) float f32x4;
typedef __attribute__((ext_vector_type(8))) short bf16x8;
typedef __attribute__((ext_vector_type(2))) unsigned short u16x2;
typedef __attribute__((ext_vector_type(4))) unsigned short u16x4;
typedef __attribute__((ext_vector_type(8))) unsigned short u16x8;

#define S_LEN 2048
#define BATCH 2
#define DMODEL 512
#define NHEAD 8
#define HDIM 64
#define MROWS 4096   // S*B
#define LAYERS 6

#define MFMA16(a, b, c) __builtin_amdgcn_mfma_f32_16x16x32_bf16((a), (b), (c), 0, 0, 0)

__device__ __forceinline__ float bf2f(unsigned short u) {
    return __uint_as_float(((unsigned)u) << 16);
}
__device__ __forceinline__ unsigned short f2bf(float f) {
    union { float f; unsigned u; } v; v.f = f;
    unsigned r = v.u + 0x7FFF + ((v.u >> 16) & 1);   // RNE
    return (unsigned short)(r >> 16);
}
__device__ __forceinline__ bf16x8 load8(const unsigned short* p) {
    return *reinterpret_cast<const bf16x8*>(p);
}

// ---------------- f32 -> bf16 bulk convert ----------------
__global__ __launch_bounds__(256) void f2bf_kernel(
    const float* __restrict__ src, unsigned short* __restrict__ dst, int n8)
{
    int i = blockIdx.x * 256 + threadIdx.x;
    if (i >= n8) return;
    f32x4 a = *reinterpret_cast<const f32x4*>(src + (size_t)i * 8);
    f32x4 b = *reinterpret_cast<const f32x4*>(src + (size_t)i * 8 + 4);
    u16x8 o;
#pragma unroll
    for (int j = 0; j < 4; ++j) { o[j] = f2bf(a[j]); o[4 + j] = f2bf(b[j]); }
    *reinterpret_cast<u16x8*>(dst + (size_t)i * 8) = o;
}

// ---------------- embedding + sinusoidal PE (double-precision PE to match np) ----------------
__global__ __launch_bounds__(256) void embed_pe_kernel(
    const int* __restrict__ seq, const float* __restrict__ emb,
    float* __restrict__ x, unsigned short* __restrict__ x16)
{
    const int r = blockIdx.x;       // 0..4095  (r = s*B + b)
    const int j = threadIdx.x;      // pair index: cols 2j, 2j+1
    const int s = r >> 1, b = r & 1;
    const int tok = seq[b * S_LEN + s];
    const float e0 = emb[(size_t)tok * DMODEL + 2 * j];
    const float e1 = emb[(size_t)tok * DMODEL + 2 * j + 1];
    const double c = -9.210340371976184 / 512.0;   // -ln(10000)/D
    double dv = exp((double)(2 * j) * c);
    double arg = (double)s * dv;
    const float v0 = e0 + (float)sin(arg);
    const float v1 = e1 + (float)cos(arg);
    x[(size_t)r * DMODEL + 2 * j]     = v0;
    x[(size_t)r * DMODEL + 2 * j + 1] = v1;
    u16x2 o; o[0] = f2bf(v0); o[1] = f2bf(v1);
    *reinterpret_cast<u16x2*>(x16 + (size_t)r * DMODEL + 2 * j) = o;
}

// ---------------- MFMA GEMM: C[M=4096,N] = A16[M,K] * W16[N,K]^T + bias ----------------
// BM x 64 tile, BK=64, 256 thr = 4 waves (2x2). Reg-prefetch double-buffered staging
// (round-13 proven version; global_load_lds variant regressed on short-K shapes).
// qkvsplit: cols [0,1024) -> Cb stride 1024 (q scaled 0.125 for col<512);
//           cols [1024,1536) -> vT (block-transposed, bit-permuted V buffer).
template<int BM>
__global__ __launch_bounds__(256) void gemm_mfma_kernel(
    const unsigned short* __restrict__ A, const unsigned short* __restrict__ W,
    const float* __restrict__ bias,
    float* __restrict__ Cf, unsigned short* __restrict__ Cb,
    unsigned short* __restrict__ vT,
    int N, int K, int relu, int qkvsplit)
{
    constexpr int MF = BM / 32;     // m-frags per wave
    __shared__ __align__(16) unsigned short As[BM * 64];
    __shared__ __align__(16) unsigned short Bs[64 * 64];
    const int tid = threadIdx.x;
    const int w = tid >> 6, lane = tid & 63, l15 = lane & 15, hi = lane >> 4;
    const int wm = w >> 1, wn = w & 1;
    const int n0 = blockIdx.x * 64, m0 = blockIdx.y * BM;
    const int sr = tid >> 3;        // staging row base 0..31
    const int ss = tid & 7;         // staging slot 0..7

    bf16x8 aprf[MF], bprf[2];
    auto loadA = [&](int k0) {
#pragma unroll
        for (int i = 0; i < MF; ++i) {
            const int r = sr + 32 * i;
            aprf[i] = load8(A + (size_t)(m0 + r) * K + k0 + ((ss ^ ((r >> 1) & 7)) * 8));
        }
    };
    auto loadB = [&](int k0) {
#pragma unroll
        for (int i = 0; i < 2; ++i) {
            const int r = sr + 32 * i;
            const int nn = n0 + r;
            if (nn < N) bprf[i] = load8(W + (size_t)nn * K + k0 + ((ss ^ ((r >> 1) & 7)) * 8));
            else { u16x8 z = {0,0,0,0,0,0,0,0}; bprf[i] = *reinterpret_cast<bf16x8*>(&z); }
        }
    };

    f32x4 acc[MF][2];
#pragma unroll
    for (int mf = 0; mf < MF; ++mf)
#pragma unroll
        for (int nf = 0; nf < 2; ++nf) acc[mf][nf] = f32x4{0.f, 0.f, 0.f, 0.f};

    loadA(0); loadB(0);
    for (int k0 = 0; k0 < K; k0 += 64) {
        __syncthreads();
#pragma unroll
        for (int i = 0; i < MF; ++i)
            *reinterpret_cast<bf16x8*>(As + (sr + 32 * i) * 64 + ss * 8) = aprf[i];
#pragma unroll
        for (int i = 0; i < 2; ++i)
            *reinterpret_cast<bf16x8*>(Bs + (sr + 32 * i) * 64 + ss * 8) = bprf[i];
        if (k0 + 64 < K) { loadA(k0 + 64); loadB(k0 + 64); }
        __syncthreads();

        bf16x8 af[MF][2], bfr[2][2];
#pragma unroll
        for (int mf = 0; mf < MF; ++mf) {
            const int r = wm * (BM / 2) + mf * 16 + l15;
            const int sw = (r >> 1) & 7;
            const unsigned short* base = As + r * 64;
            af[mf][0] = *reinterpret_cast<const bf16x8*>(base + ((hi ^ sw) * 8));
            af[mf][1] = *reinterpret_cast<const bf16x8*>(base + (((hi + 4) ^ sw) * 8));
        }
#pragma unroll
        for (int nf = 0; nf < 2; ++nf) {
            const int r = wn * 32 + nf * 16 + l15;
            const int sw = (r >> 1) & 7;
            const unsigned short* base = Bs + r * 64;
            bfr[nf][0] = *reinterpret_cast<const bf16x8*>(base + ((hi ^ sw) * 8));
            bfr[nf][1] = *reinterpret_cast<const bf16x8*>(base + (((hi + 4) ^ sw) * 8));
        }
#pragma unroll
        for (int mf = 0; mf < MF; ++mf)
#pragma unroll
            for (int nf = 0; nf < 2; ++nf) {
                acc[mf][nf] = MFMA16(af[mf][0], bfr[nf][0], acc[mf][nf]);
                acc[mf][nf] = MFMA16(af[mf][1], bfr[nf][1], acc[mf][nf]);
            }
    }

    // ---- epilogue: bias (+relu) -> f32 / bf16 / split qk+vT ----
#pragma unroll
    for (int nf = 0; nf < 2; ++nf) {
        const int col = n0 + wn * 32 + nf * 16 + l15;
        const bool okc = col < N;
        const float bv = okc ? bias[col] : 0.f;
#pragma unroll
        for (int mf = 0; mf < MF; ++mf) {
            const int rbase = m0 + wm * (BM / 2) + mf * 16 + hi * 4;
#pragma unroll
            for (int rg = 0; rg < 4; ++rg) {
                float v = acc[mf][nf][rg] + bv;
                if (relu) v = fmaxf(v, 0.f);
                if (okc) {
                    const int row = rbase + rg;
                    if (qkvsplit) {
                        if (col < 1024) {
                            if (col < 512) v *= 0.125f;
                            Cb[(size_t)row * 1024 + col] = f2bf(v);
                        } else {
                            const int h = (col - 1024) >> 6, d = (col - 1024) & 63;
                            const int s = row >> 1, bb = row & 1;
                            const int kt = s >> 6, kin = s & 63;
                            const int pos = (kin & 3) | (((kin >> 4) & 1) << 2)
                                          | (((kin >> 2) & 3) << 3) | (kin & 32);
                            vT[((((size_t)(bb * 8 + h) * 32 + kt) * 64 + d) << 6) + pos] = f2bf(v);
                        }
                    } else {
                        const size_t idx = (size_t)row * N + col;
                        if (Cb) Cb[idx] = f2bf(v);
                        else    Cf[idx] = v;
                    }
                }
            }
        }
    }
}

// ---------------- MFMA flash attention, KV-split (512-key chunks), heavy-first ----------------
// qk16: [r=s*B+b][1024] bf16 (q pre-scaled | k). vT16: [bh][kt][d][pos(k)] bf16.
// er16: [2048][64] bf16. srel[q,k] = q.er[2047-q+k], k<=q.
// Grid (16 bh fast, 80 tasks slow). GLOBAL heavy-first task order:
//   bx<25:  c=0, qb=31-bx          (ntl=8)
//   bx<42:  c=1, qb=31-(bx-25)     (ntl=8)
//   bx<51:  c=2, qb=31-(bx-42)     (ntl=8)
//   bx==51: c=3, qb=31             (ntl=8)
//   else:   lev=(bx-52)>>2, c=(bx-52)&3, qb=8c+6-lev  (ntl=7-lev)
__global__ __launch_bounds__(256, 2) void attn_mfma_kernel(
    const unsigned short* __restrict__ qk16, const unsigned short* __restrict__ vT16,
    const unsigned short* __restrict__ er16,
    unsigned short* __restrict__ part16, float* __restrict__ mlbuf)
{
    __shared__ __align__(16) unsigned short K_s[64 * 64];     // [k][d] granule-swizzled
    __shared__ __align__(16) unsigned short V_T[64 * 64];     // [d][pos(k)] granule-swizzled
    __shared__ __align__(16) unsigned short Er_s[64 * 64];    // er rows fb..fb+63, swizzled
    __shared__ __align__(16) unsigned short E_w[4 * 16 * 196];// per-wave [q=16][192+4]

    const int tid  = threadIdx.x;
    const int w    = tid >> 6;
    const int lane = tid & 63;
    const int l15  = lane & 15;
    const int hi   = lane >> 4;
    const int bx   = blockIdx.y;        // task 0..79 (slow axis, heavy first)
    const int bh   = blockIdx.x;        // 0..15
    const int b    = bh >> 3, hh = bh & 7;
    const int sk   = lane;              // K staging k-row
    const int dg0  = w;                 // K staging d-granules w, w+4
    const int dv0  = 16 * w + (lane >> 3);      // V staging d-rows dv0, dv0+8
    const int gv   = lane & 7;                  // V staging granule

    int qb, c;
    if (bx < 25)       { c = 0; qb = 31 - bx; }
    else if (bx < 42)  { c = 1; qb = 31 - (bx - 25); }
    else if (bx < 51)  { c = 2; qb = 31 - (bx - 42); }
    else if (bx == 51) { c = 3; qb = 31; }
    else { const int lev = (bx - 52) >> 2; c = (bx - 52) & 3; qb = 8 * c + 6 - lev; }
    const int pidx = bh * 80 + bx;
    const int q0   = qb * 64;
    const int k0s  = c * 512;
    const int ntl  = min(qb + 1 - c * 8, 8);     // tiles in this chunk (1..8)
    const int qg   = q0 + 16 * w + l15;

    const unsigned short* qptr = qk16 + ((size_t)qg * BATCH + b) * 1024 + hh * HDIM;
    bf16x8 qf0 = load8(qptr + hi * 8);
    bf16x8 qf1 = load8(qptr + 32 + hi * 8);

    unsigned short* ewp = E_w + (w * 16 + l15) * 196;
    const int E0  = 1984 - q0 + k0s;
    const int E0m = E0 % 192;

    // ---- prologue: QE rows [E0, E0+127] (direct global, once per block) ----
#pragma unroll 2
    for (int mf = 0; mf < 8; ++mf) {
        int e = E0 + mf * 16 + l15;
        int ec = e > 2047 ? 2047 : e;    // clamped rows are causally masked later
        bf16x8 a0 = load8(er16 + (size_t)ec * 64 + hi * 8);
        bf16x8 a1 = load8(er16 + (size_t)ec * 64 + 32 + hi * 8);
        f32x4 acc = {0.f, 0.f, 0.f, 0.f};
        acc = MFMA16(a0, qf0, acc);
        acc = MFMA16(a1, qf1, acc);
        int col = E0m + mf * 16 + 4 * hi;
        if (col >= 192) col -= 192;
        u16x4 ew;
#pragma unroll
        for (int r = 0; r < 4; ++r) ew[r] = f2bf(acc[r]);
        *reinterpret_cast<u16x4*>(ewp + col) = ew;
    }

    float m = -INFINITY, lsum = 0.f;
    f32x4 acc_o[4];
#pragma unroll
    for (int mf = 0; mf < 4; ++mf) acc_o[mf] = f32x4{0.f, 0.f, 0.f, 0.f};

    int col0t = (2047 - qg + k0s) % 192;

    // ---- prefetch tile 0 K/V into regs (+ er rows for tile 0's QE-next) ----
    bf16x8 kpr0, kpr1, vpr0, vpr1, epr0, epr1;
    {
        const unsigned short* krow = qk16 + ((size_t)(k0s + sk) * BATCH + b) * 1024 + 512 + hh * HDIM;
        kpr0 = load8(krow + dg0 * 8);       kpr1 = load8(krow + (dg0 + 4) * 8);
        const unsigned short* vbase = vT16 + (((size_t)bh * 32 + (k0s >> 6)) * 64) * 64;
        vpr0 = load8(vbase + dv0 * 64 + gv * 8);
        vpr1 = load8(vbase + (dv0 + 8) * 64 + gv * 8);
    }
    if (ntl > 1) {
        int e = E0 + 128 + sk;
        int ec = e > 2047 ? 2047 : e;
        epr0 = load8(er16 + (size_t)ec * 64 + dg0 * 8);
        epr1 = load8(er16 + (size_t)ec * 64 + (dg0 + 4) * 8);
    }

    for (int t = 0; t < ntl; ++t) {
        const int k0 = k0s + t * 64;
        const bool doE = (t + 1 < ntl);
        __syncthreads();
        // ---- write prefetched K, V^T, Er (all swizzled b128) ----
        *reinterpret_cast<bf16x8*>(K_s + sk * 64 + ((dg0 ^ (sk & 7)) * 8)) = kpr0;
        *reinterpret_cast<bf16x8*>(K_s + sk * 64 + (((dg0 + 4) ^ (sk & 7)) * 8)) = kpr1;
        *reinterpret_cast<bf16x8*>(V_T + dv0 * 64 + ((gv ^ (dv0 & 7)) * 8)) = vpr0;
        *reinterpret_cast<bf16x8*>(V_T + (dv0 + 8) * 64 + ((gv ^ (dv0 & 7)) * 8)) = vpr1;
        if (doE) {
            *reinterpret_cast<bf16x8*>(Er_s + sk * 64 + ((dg0 ^ (sk & 7)) * 8)) = epr0;
            *reinterpret_cast<bf16x8*>(Er_s + sk * 64 + (((dg0 + 4) ^ (sk & 7)) * 8)) = epr1;
        }
        // ---- prefetch next tile's K/V (+ er rows for next tile's QE) ----
        if (t + 1 < ntl) {
            const unsigned short* krow = qk16 + ((size_t)(k0 + 64 + sk) * BATCH + b) * 1024 + 512 + hh * HDIM;
            kpr0 = load8(krow + dg0 * 8);       kpr1 = load8(krow + (dg0 + 4) * 8);
            const unsigned short* vbase = vT16 + (((size_t)bh * 32 + ((k0 + 64) >> 6)) * 64) * 64;
            vpr0 = load8(vbase + dv0 * 64 + gv * 8);
            vpr1 = load8(vbase + (dv0 + 8) * 64 + gv * 8);
            if (t + 2 < ntl) {
                int e = E0 + 128 + 64 * (t + 1) + sk;
                int ec = e > 2047 ? 2047 : e;
                epr0 = load8(er16 + (size_t)ec * 64 + dg0 * 8);
                epr1 = load8(er16 + (size_t)ec * 64 + (dg0 + 4) * 8);
            }
        }
        __syncthreads();

        // ---- QK: S^T[k][q] = K x Q ----
        f32x4 sacc[4];
#pragma unroll
        for (int f = 0; f < 4; ++f) {
            const int row = l15 + 16 * f;
            bf16x8 ka0 = *reinterpret_cast<const bf16x8*>(K_s + row * 64 + (((0 + hi) ^ (l15 & 7)) * 8));
            bf16x8 ka1 = *reinterpret_cast<const bf16x8*>(K_s + row * 64 + (((4 + hi) ^ (l15 & 7)) * 8));
            f32x4 z = {0.f, 0.f, 0.f, 0.f};
            z = MFMA16(ka0, qf0, z);
            sacc[f] = MFMA16(ka1, qf1, z);
        }

        // ---- QE for next tile: A-frags from Er_s ----
        if (doE) {
            const int fbm = (E0 + 128 + 64 * t) % 192;
#pragma unroll
            for (int mf = 0; mf < 4; ++mf) {
                const int rr = l15 + 16 * mf;
                bf16x8 a0 = *reinterpret_cast<const bf16x8*>(Er_s + rr * 64 + ((hi ^ (l15 & 7)) * 8));
                bf16x8 a1 = *reinterpret_cast<const bf16x8*>(Er_s + rr * 64 + (((hi + 4) ^ (l15 & 7)) * 8));
                f32x4 acc = {0.f, 0.f, 0.f, 0.f};
                acc = MFMA16(a0, qf0, acc);
                acc = MFMA16(a1, qf1, acc);
                int col = fbm + mf * 16 + 4 * hi;
                u16x4 ew;
#pragma unroll
                for (int r = 0; r < 4; ++r) ew[r] = f2bf(acc[r]);
                *reinterpret_cast<u16x4*>(ewp + col) = ew;
            }
        }

        // ---- gather QE diagonal + causal mask + online softmax (in-place) ----
        float mt = -INFINITY;
#pragma unroll
        for (int f = 0; f < 4; ++f) {
#pragma unroll
            for (int r = 0; r < 4; ++r) {
                const int kk = 16 * f + 4 * hi + r;
                int col = col0t + kk;
                if (col >= 192) col -= 192;
                float sv = sacc[f][r] + bf2f(ewp[col]);
                if (k0 + kk > qg) sv = -1e9f;
                sacc[f][r] = sv;
                mt = fmaxf(mt, sv);
            }
        }
        mt = fmaxf(mt, __shfl_xor(mt, 16));
        mt = fmaxf(mt, __shfl_xor(mt, 32));
        const float mn = fmaxf(m, mt);
        const float corr = __expf(m - mn);
        float ps = 0.f;
#pragma unroll
        for (int f = 0; f < 4; ++f)
#pragma unroll
            for (int r = 0; r < 4; ++r) {
                const float e = __expf(sacc[f][r] - mn);
                sacc[f][r] = e; ps += e;
            }
        ps += __shfl_xor(ps, 16);
        ps += __shfl_xor(ps, 32);
        lsum = lsum * corr + ps;
        m = mn;

        // ---- pack P to bf16 B-frags ----
        bf16x8 pf0, pf1;
#pragma unroll
        for (int j = 0; j < 8; ++j) {
            pf0[j] = (short)f2bf(sacc[j >> 2][j & 3]);
            pf1[j] = (short)f2bf(sacc[(j >> 2) + 2][j & 3]);
        }

        // ---- rescale + PV: ctx^T = V^T x P (direct b128 A-frags) ----
#pragma unroll
        for (int mf = 0; mf < 4; ++mf) {
            f32x4 a = acc_o[mf];
            a[0] *= corr; a[1] *= corr; a[2] *= corr; a[3] *= corr;
            const unsigned short* vrow = V_T + (l15 + 16 * mf) * 64;
            const int sw = l15 & 7;
            bf16x8 vf0 = *reinterpret_cast<const bf16x8*>(vrow + ((hi ^ sw) * 8));
            bf16x8 vf1 = *reinterpret_cast<const bf16x8*>(vrow + (((4 + hi) ^ sw) * 8));
            a = MFMA16(vf0, pf0, a);
            a = MFMA16(vf1, pf1, a);
            acc_o[mf] = a;
        }

        col0t += 64;
        if (col0t >= 192) col0t -= 192;
    }

    // ---- epilogue: write un-normalized partials ----
    unsigned short* pa = part16 + ((size_t)pidx * 64 + 16 * w + l15) * 64;
#pragma unroll
    for (int mf = 0; mf < 4; ++mf) {
        u16x4 o;
#pragma unroll
        for (int r = 0; r < 4; ++r) o[r] = f2bf(acc_o[mf][r]);
        *reinterpret_cast<u16x4*>(pa + 16 * mf + 4 * hi) = o;
    }
    if (hi == 0) {
        float* ml = mlbuf + ((size_t)pidx * 64 + 16 * w + l15) * 2;
        ml[0] = m; ml[1] = lsum;
    }
}

// ---------------- combine partials -> ctx16 (up to 4 chunks, online merge) ----------------
// inverse of the heavy-first task mapping:
//   chunk cc of qb: if qb-8cc>=7 -> idx = {0,25,42,51}[cc] + (31-qb)
//                   else          -> idx = 52 + 4*(6-(qb-8cc)) + cc
__global__ __launch_bounds__(256) void attn_combine_kernel(
    const unsigned short* __restrict__ part16, const float* __restrict__ mlbuf,
    unsigned short* __restrict__ ctx16)
{
    const int flat = blockIdx.x * 256 + threadIdx.x;
    const int qi = flat >> 3, dg = flat & 7;
    const int bh = qi >> 11, ql = qi & 2047;
    const int b = bh >> 3, hh = bh & 7;
    const int qb = ql >> 6, rl = ql & 63;

    const int nch = (qb >> 3) + 1;              // 1..4 chunks
    float mr = -1e30f, lr = 0.f;
    float o[8];
#pragma unroll
    for (int j = 0; j < 8; ++j) o[j] = 0.f;

    for (int cc = 0; cc < nch; ++cc) {
        int idx;
        if (qb - 8 * cc >= 7) {
            const int base = (cc == 0) ? 0 : (cc == 1) ? 25 : (cc == 2) ? 42 : 51;
            idx = bh * 80 + base + (31 - qb);
        } else {
            idx = bh * 80 + 52 + 4 * (6 - (qb - 8 * cc)) + cc;
        }
        const float* ml = mlbuf + ((size_t)idx * 64 + rl) * 2;
        const float mc = ml[0], lc = ml[1];
        u16x8 a = *reinterpret_cast<const u16x8*>(part16 + ((size_t)idx * 64 + rl) * 64 + dg * 8);
        const float mn = fmaxf(mr, mc);
        const float w0 = __expf(mr - mn), w1 = __expf(mc - mn);
#pragma unroll
        for (int j = 0; j < 8; ++j) o[j] = o[j] * w0 + bf2f(a[j]) * w1;
        lr = lr * w0 + lc * w1;
        mr = mn;
    }
    const float inv = 1.f / lr;
    u16x8 res;
#pragma unroll
    for (int j = 0; j < 8; ++j) res[j] = f2bf(o[j] * inv);
    *reinterpret_cast<u16x8*>(ctx16 + ((size_t)ql * BATCH + b) * DMODEL + hh * HDIM + dg * 8) = res;
}

// ---------------- LayerNorm (fused residual add), writes f32 + bf16 ----------------
__global__ __launch_bounds__(256) void ln_kernel(
    const float* __restrict__ xin, const float* __restrict__ res,
    const float* __restrict__ gg, const float* __restrict__ bb,
    float* __restrict__ xout, unsigned short* __restrict__ x16out, int has_res)
{
    const int w = threadIdx.x >> 6, lane = threadIdx.x & 63;
    const int row = blockIdx.x * 4 + w;
    const float* xp = xin + (size_t)row * DMODEL + lane * 8;
    f32x4 v0 = *reinterpret_cast<const f32x4*>(xp);
    f32x4 v1 = *reinterpret_cast<const f32x4*>(xp + 4);
    if (has_res) {
        const float* rp = res + (size_t)row * DMODEL + lane * 8;
        v0 += *reinterpret_cast<const f32x4*>(rp);
        v1 += *reinterpret_cast<const f32x4*>(rp + 4);
    }
    float sum = 0.f, ssq = 0.f;
#pragma unroll
    for (int c2 = 0; c2 < 4; ++c2) {
        sum += v0[c2] + v1[c2];
        ssq += v0[c2] * v0[c2] + v1[c2] * v1[c2];
    }
#pragma unroll
    for (int off = 32; off > 0; off >>= 1) {
        sum += __shfl_xor(sum, off);
        ssq += __shfl_xor(ssq, off);
    }
    const float mu = sum * (1.f / 512.f);
    const float var = ssq * (1.f / 512.f) - mu * mu;
    const float rstd = rsqrtf(var + 1e-5f);
    f32x4 g0 = *reinterpret_cast<const f32x4*>(gg + lane * 8);
    f32x4 g1 = *reinterpret_cast<const f32x4*>(gg + lane * 8 + 4);
    f32x4 b0 = *reinterpret_cast<const f32x4*>(bb + lane * 8);
    f32x4 b1 = *reinterpret_cast<const f32x4*>(bb + lane * 8 + 4);
    f32x4 o0, o1;
    u16x8 h;
#pragma unroll
    for (int c2 = 0; c2 < 4; ++c2) {
        o0[c2] = (v0[c2] - mu) * rstd * g0[c2] + b0[c2];
        o1[c2] = (v1[c2] - mu) * rstd * g1[c2] + b1[c2];
        h[c2] = f2bf(o0[c2]); h[4 + c2] = f2bf(o1[c2]);
    }
    float* op = xout + (size_t)row * DMODEL + lane * 8;
    *reinterpret_cast<f32x4*>(op)     = o0;
    *reinterpret_cast<f32x4*>(op + 4) = o1;
    *reinterpret_cast<u16x8*>(x16out + (size_t)row * DMODEL + lane * 8) = h;
}

// ---------------- host launch ----------------
extern "C" void kernel_launch(void* const* d_in, const int* in_sizes, int n_in,
                              void* d_out, int out_size, void* d_ws, size_t ws_size,
                              hipStream_t stream)
{
    const int*   seq  = (const int*)d_in[0];
    const float* emb  = (const float*)d_in[1];
    const float* ipw  = (const float*)d_in[2];
    const float* ipb  = (const float*)d_in[3];
    const float* opw  = (const float*)d_in[4];
    const float* opb  = (const float*)d_in[5];
    const float* er   = (const float*)d_in[6];
    const float* l1w  = (const float*)d_in[7];
    const float* l1b  = (const float*)d_in[8];
    const float* l2w  = (const float*)d_in[9];
    const float* l2b  = (const float*)d_in[10];
    const float* ln1g = (const float*)d_in[11];
    const float* ln1b = (const float*)d_in[12];
    const float* ln2g = (const float*)d_in[13];
    const float* ln2b = (const float*)d_in[14];
    const float* flng = (const float*)d_in[15];
    const float* flnb = (const float*)d_in[16];
    const float* ww   = (const float*)d_in[17];
    const float* wb   = (const float*)d_in[18];
    float* out = (float*)d_out;

    float* xf  = (float*)d_ws;                               // [4096][512] f32
    float* tmp = xf + (size_t)MROWS * DMODEL;                // [4096][512] f32
    unsigned short* x16   = (unsigned short*)(tmp + (size_t)MROWS * DMODEL);  // [4096][512]
    unsigned short* qk16  = x16  + (size_t)MROWS * DMODEL;   // [4096][1024] (h16 aliases)
    unsigned short* ctx16 = qk16 + (size_t)MROWS * 1024;     // [4096][512]
    unsigned short* er16  = ctx16 + (size_t)MROWS * DMODEL;  // [6][2048][64]
    unsigned short* vT16  = er16 + (size_t)LAYERS * S_LEN * HDIM;  // [16][32][64][64]
    unsigned short* w16   = vT16 + (size_t)16 * 32 * 64 * 64;
    unsigned short* h16   = qk16;                            // alias (disjoint lifetime)
    // attention partials overlay tmp+x16 (both dead during attn -> combine):
    unsigned short* part16 = (unsigned short*)tmp;
    float* mlbuf = (float*)(part16 + (size_t)1280 * 64 * 64);

    unsigned short* ipw16 = w16;                             // 6*1536*512
    unsigned short* opw16 = ipw16 + (size_t)LAYERS * 1536 * DMODEL;
    unsigned short* l1w16 = opw16 + (size_t)LAYERS * DMODEL * DMODEL;
    unsigned short* l2w16 = l1w16 + (size_t)LAYERS * 1024 * DMODEL;
    unsigned short* ww16  = l2w16 + (size_t)LAYERS * DMODEL * 1024;

    // ---- weight + er conversion (once per launch) ----
    {
        int n8;
        n8 = LAYERS * 1536 * DMODEL / 8; f2bf_kernel<<<(n8 + 255) / 256, 256, 0, stream>>>(ipw, ipw16, n8);
        n8 = LAYERS * DMODEL * DMODEL / 8; f2bf_kernel<<<(n8 + 255) / 256, 256, 0, stream>>>(opw, opw16, n8);
        n8 = LAYERS * 1024 * DMODEL / 8; f2bf_kernel<<<(n8 + 255) / 256, 256, 0, stream>>>(l1w, l1w16, n8);
        n8 = LAYERS * DMODEL * 1024 / 8; f2bf_kernel<<<(n8 + 255) / 256, 256, 0, stream>>>(l2w, l2w16, n8);
        n8 = 267 * DMODEL / 8;           f2bf_kernel<<<(n8 + 255) / 256, 256, 0, stream>>>(ww, ww16, n8);
        n8 = LAYERS * S_LEN * HDIM / 8;  f2bf_kernel<<<(n8 + 255) / 256, 256, 0, stream>>>(er, er16, n8);
    }

    embed_pe_kernel<<<MROWS, 256, 0, stream>>>(seq, emb, xf, x16);

    for (int i = 0; i < LAYERS; ++i) {
        gemm_mfma_kernel<128><<<dim3(24, 32), 256, 0, stream>>>(
            x16, ipw16 + (size_t)i * 1536 * DMODEL, ipb + (size_t)i * 1536,
            nullptr, qk16, vT16, 1536, DMODEL, 0, 1);
        attn_mfma_kernel<<<dim3(BATCH * NHEAD, 80), 256, 0, stream>>>(
            qk16, vT16, er16 + (size_t)i * S_LEN * HDIM, part16, mlbuf);
        attn_combine_kernel<<<1024, 256, 0, stream>>>(part16, mlbuf, ctx16);
        gemm_mfma_kernel<64><<<dim3(8, 64), 256, 0, stream>>>(
            ctx16, opw16 + (size_t)i * DMODEL * DMODEL, opb + (size_t)i * DMODEL,
            tmp, nullptr, nullptr, DMODEL, DMODEL, 0, 0);
        ln_kernel<<<MROWS / 4, 256, 0, stream>>>(
            xf, tmp, ln1g + (size_t)i * DMODEL, ln1b + (size_t)i * DMODEL, xf, x16, 1);
        gemm_mfma_kernel<128><<<dim3(16, 32), 256, 0, stream>>>(
            x16, l1w16 + (size_t)i * 1024 * DMODEL, l1b + (size_t)i * 1024,
            nullptr, h16, nullptr, 1024, DMODEL, 1, 0);
        gemm_mfma_kernel<64><<<dim3(8, 64), 256, 0, stream>>>(
            h16, l2w16 + (size_t)i * DMODEL * 1024, l2b + (size_t)i * DMODEL,
            tmp, nullptr, nullptr, DMODEL, 1024, 0, 0);
        ln_kernel<<<MROWS / 4, 256, 0, stream>>>(
            xf, tmp, ln2g + (size_t)i * DMODEL, ln2b + (size_t)i * DMODEL, xf, x16, 1);
    }

    ln_kernel<<<MROWS / 4, 256, 0, stream>>>(xf, nullptr, flng, flnb, xf, x16, 0);
    gemm_mfma_kernel<64><<<dim3(5, 64), 256, 0, stream>>>(
        x16, ww16, wb, out, nullptr, nullptr, 267, DMODEL, 0, 0);
}

// Round 16
// 712.624 us; speedup vs baseline: 1.0632x; 1.0039x over previous
//
#include <hip/hip_runtime.h>
#include <hip/hip_bf16.h>

typedef __attribute__((ext_vector_type(4))) float f32x4;
typedef __attribute__((ext_vector_type(8))) short bf16x8;
typedef __attribute__((ext_vector_type(2))) unsigned short u16x2;
typedef __attribute__((ext_vector_type(4))) unsigned short u16x4;
typedef __attribute__((ext_vector_type(8))) unsigned short u16x8;

#define S_LEN 2048
#define BATCH 2
#define DMODEL 512
#define NHEAD 8
#define HDIM 64
#define MROWS 4096   // S*B
#define LAYERS 6

#define MFMA16(a, b, c) __builtin_amdgcn_mfma_f32_16x16x32_bf16((a), (b), (c), 0, 0, 0)

__device__ __forceinline__ float bf2f(unsigned short u) {
    return __uint_as_float(((unsigned)u) << 16);
}
__device__ __forceinline__ unsigned short f2bf(float f) {
    __hip_bfloat16 h = __float2bfloat16(f);   // HW cvt (RNE), 1 VALU
    return *reinterpret_cast<unsigned short*>(&h);
}
__device__ __forceinline__ bf16x8 load8(const unsigned short* p) {
    return *reinterpret_cast<const bf16x8*>(p);
}

// ---------------- f32 -> bf16 bulk convert ----------------
__global__ __launch_bounds__(256) void f2bf_kernel(
    const float* __restrict__ src, unsigned short* __restrict__ dst, int n8)
{
    int i = blockIdx.x * 256 + threadIdx.x;
    if (i >= n8) return;
    f32x4 a = *reinterpret_cast<const f32x4*>(src + (size_t)i * 8);
    f32x4 b = *reinterpret_cast<const f32x4*>(src + (size_t)i * 8 + 4);
    u16x8 o;
#pragma unroll
    for (int j = 0; j < 4; ++j) { o[j] = f2bf(a[j]); o[4 + j] = f2bf(b[j]); }
    *reinterpret_cast<u16x8*>(dst + (size_t)i * 8) = o;
}

// ---------------- embedding + sinusoidal PE (double-precision PE to match np) ----------------
__global__ __launch_bounds__(256) void embed_pe_kernel(
    const int* __restrict__ seq, const float* __restrict__ emb,
    float* __restrict__ x, unsigned short* __restrict__ x16)
{
    const int r = blockIdx.x;       // 0..4095  (r = s*B + b)
    const int j = threadIdx.x;      // pair index: cols 2j, 2j+1
    const int s = r >> 1, b = r & 1;
    const int tok = seq[b * S_LEN + s];
    const float e0 = emb[(size_t)tok * DMODEL + 2 * j];
    const float e1 = emb[(size_t)tok * DMODEL + 2 * j + 1];
    const double c = -9.210340371976184 / 512.0;   // -ln(10000)/D
    double dv = exp((double)(2 * j) * c);
    double arg = (double)s * dv;
    const float v0 = e0 + (float)sin(arg);
    const float v1 = e1 + (float)cos(arg);
    x[(size_t)r * DMODEL + 2 * j]     = v0;
    x[(size_t)r * DMODEL + 2 * j + 1] = v1;
    u16x2 o; o[0] = f2bf(v0); o[1] = f2bf(v1);
    *reinterpret_cast<u16x2*>(x16 + (size_t)r * DMODEL + 2 * j) = o;
}

// ---------------- MFMA GEMM: C[M=4096,N] = A16[M,K] * W16[N,K]^T + bias ----------------
// BM x 64 tile, BK=64, 256 thr = 4 waves (2x2). Reg-prefetch double-buffered staging.
// qkvsplit: cols [0,1024) -> Cb stride 1024 (q scaled 0.125 for col<512);
//           cols [1024,1536) -> vT (block-transposed, bit-permuted V buffer).
template<int BM>
__global__ __launch_bounds__(256) void gemm_mfma_kernel(
    const unsigned short* __restrict__ A, const unsigned short* __restrict__ W,
    const float* __restrict__ bias,
    float* __restrict__ Cf, unsigned short* __restrict__ Cb,
    unsigned short* __restrict__ vT,
    int N, int K, int relu, int qkvsplit)
{
    constexpr int MF = BM / 32;     // m-frags per wave
    __shared__ __align__(16) unsigned short As[BM * 64];
    __shared__ __align__(16) unsigned short Bs[64 * 64];
    const int tid = threadIdx.x;
    const int w = tid >> 6, lane = tid & 63, l15 = lane & 15, hi = lane >> 4;
    const int wm = w >> 1, wn = w & 1;
    const int n0 = blockIdx.x * 64, m0 = blockIdx.y * BM;
    const int sr = tid >> 3;        // staging row base 0..31
    const int ss = tid & 7;         // staging slot 0..7

    bf16x8 aprf[MF], bprf[2];
    auto loadA = [&](int k0) {
#pragma unroll
        for (int i = 0; i < MF; ++i) {
            const int r = sr + 32 * i;
            aprf[i] = load8(A + (size_t)(m0 + r) * K + k0 + ((ss ^ ((r >> 1) & 7)) * 8));
        }
    };
    auto loadB = [&](int k0) {
#pragma unroll
        for (int i = 0; i < 2; ++i) {
            const int r = sr + 32 * i;
            const int nn = n0 + r;
            if (nn < N) bprf[i] = load8(W + (size_t)nn * K + k0 + ((ss ^ ((r >> 1) & 7)) * 8));
            else { u16x8 z = {0,0,0,0,0,0,0,0}; bprf[i] = *reinterpret_cast<bf16x8*>(&z); }
        }
    };

    f32x4 acc[MF][2];
#pragma unroll
    for (int mf = 0; mf < MF; ++mf)
#pragma unroll
        for (int nf = 0; nf < 2; ++nf) acc[mf][nf] = f32x4{0.f, 0.f, 0.f, 0.f};

    loadA(0); loadB(0);
    for (int k0 = 0; k0 < K; k0 += 64) {
        __syncthreads();
#pragma unroll
        for (int i = 0; i < MF; ++i)
            *reinterpret_cast<bf16x8*>(As + (sr + 32 * i) * 64 + ss * 8) = aprf[i];
#pragma unroll
        for (int i = 0; i < 2; ++i)
            *reinterpret_cast<bf16x8*>(Bs + (sr + 32 * i) * 64 + ss * 8) = bprf[i];
        if (k0 + 64 < K) { loadA(k0 + 64); loadB(k0 + 64); }
        __syncthreads();

        bf16x8 af[MF][2], bfr[2][2];
#pragma unroll
        for (int mf = 0; mf < MF; ++mf) {
            const int r = wm * (BM / 2) + mf * 16 + l15;
            const int sw = (r >> 1) & 7;
            const unsigned short* base = As + r * 64;
            af[mf][0] = *reinterpret_cast<const bf16x8*>(base + ((hi ^ sw) * 8));
            af[mf][1] = *reinterpret_cast<const bf16x8*>(base + (((hi + 4) ^ sw) * 8));
        }
#pragma unroll
        for (int nf = 0; nf < 2; ++nf) {
            const int r = wn * 32 + nf * 16 + l15;
            const int sw = (r >> 1) & 7;
            const unsigned short* base = Bs + r * 64;
            bfr[nf][0] = *reinterpret_cast<const bf16x8*>(base + ((hi ^ sw) * 8));
            bfr[nf][1] = *reinterpret_cast<const bf16x8*>(base + (((hi + 4) ^ sw) * 8));
        }
#pragma unroll
        for (int mf = 0; mf < MF; ++mf)
#pragma unroll
            for (int nf = 0; nf < 2; ++nf) {
                acc[mf][nf] = MFMA16(af[mf][0], bfr[nf][0], acc[mf][nf]);
                acc[mf][nf] = MFMA16(af[mf][1], bfr[nf][1], acc[mf][nf]);
            }
    }

    // ---- epilogue: bias (+relu) -> f32 / bf16 / split qk+vT ----
#pragma unroll
    for (int nf = 0; nf < 2; ++nf) {
        const int col = n0 + wn * 32 + nf * 16 + l15;
        const bool okc = col < N;
        const float bv = okc ? bias[col] : 0.f;
#pragma unroll
        for (int mf = 0; mf < MF; ++mf) {
            const int rbase = m0 + wm * (BM / 2) + mf * 16 + hi * 4;
#pragma unroll
            for (int rg = 0; rg < 4; ++rg) {
                float v = acc[mf][nf][rg] + bv;
                if (relu) v = fmaxf(v, 0.f);
                if (okc) {
                    const int row = rbase + rg;
                    if (qkvsplit) {
                        if (col < 1024) {
                            if (col < 512) v *= 0.125f;
                            Cb[(size_t)row * 1024 + col] = f2bf(v);
                        } else {
                            const int h = (col - 1024) >> 6, d = (col - 1024) & 63;
                            const int s = row >> 1, bb = row & 1;
                            const int kt = s >> 6, kin = s & 63;
                            const int pos = (kin & 3) | (((kin >> 4) & 1) << 2)
                                          | (((kin >> 2) & 3) << 3) | (kin & 32);
                            vT[((((size_t)(bb * 8 + h) * 32 + kt) * 64 + d) << 6) + pos] = f2bf(v);
                        }
                    } else {
                        const size_t idx = (size_t)row * N + col;
                        if (Cb) Cb[idx] = f2bf(v);
                        else    Cf[idx] = v;
                    }
                }
            }
        }
    }
}

// ---------------- MFMA flash attention, KV-split (512-key chunks), in-tile QE ----------------
// qk16: [r=s*B+b][1024] bf16 (q pre-scaled | k). vT16: [bh][kt][d][pos(k)] bf16.
// er16: [2048][64] bf16. srel[q,k] = q.er[2047-q+k], k<=q.
// Er staged in 128-row LDS ring (positions = er-offset-index & 127); QE computed
// IN-TILE: E_w[q][j] = QE[q][E0+64t+48-16w+j], gather col j = (15-l15)+kk <= 78.
// Grid (16 bh fast, 80 tasks slow), GLOBAL heavy-first task order (round-15).
__global__ __launch_bounds__(256, 2) void attn_mfma_kernel(
    const unsigned short* __restrict__ qk16, const unsigned short* __restrict__ vT16,
    const unsigned short* __restrict__ er16,
    unsigned short* __restrict__ part16, float* __restrict__ mlbuf)
{
    __shared__ __align__(16) unsigned short K_s[64 * 64];     // [k][d] granule-swizzled
    __shared__ __align__(16) unsigned short V_T[64 * 64];     // [d][pos(k)] granule-swizzled
    __shared__ __align__(16) unsigned short Er_s[128 * 64];   // ring, granule-swizzled
    __shared__ __align__(16) unsigned short E_w[4 * 16 * 84]; // per-wave [q=16][84]

    const int tid  = threadIdx.x;
    const int w    = tid >> 6;
    const int lane = tid & 63;
    const int l15  = lane & 15;
    const int hi   = lane >> 4;
    const int bx   = blockIdx.y;        // task 0..79 (slow axis, heavy first)
    const int bh   = blockIdx.x;        // 0..15
    const int b    = bh >> 3, hh = bh & 7;
    const int sk   = lane;              // K/Er staging row
    const int dg0  = w;                 // K/Er staging d-granules w, w+4
    const int dv0  = 16 * w + (lane >> 3);      // V staging d-rows dv0, dv0+8
    const int gv   = lane & 7;                  // V staging granule

    int qb, c;
    if (bx < 25)       { c = 0; qb = 31 - bx; }
    else if (bx < 42)  { c = 1; qb = 31 - (bx - 25); }
    else if (bx < 51)  { c = 2; qb = 31 - (bx - 42); }
    else if (bx == 51) { c = 3; qb = 31; }
    else { const int lev = (bx - 52) >> 2; c = (bx - 52) & 3; qb = 8 * c + 6 - lev; }
    const int pidx = bh * 80 + bx;
    const int q0   = qb * 64;
    const int k0s  = c * 512;
    const int ntl  = min(qb + 1 - c * 8, 8);     // tiles in this chunk (1..8)
    const int qg   = q0 + 16 * w + l15;

    const unsigned short* qptr = qk16 + ((size_t)qg * BATCH + b) * 1024 + hh * HDIM;
    bf16x8 qf0 = load8(qptr + hi * 8);
    bf16x8 qf1 = load8(qptr + 32 + hi * 8);

    unsigned short* ewp = E_w + (w * 16 + l15) * 84;
    const int E0 = 1984 - q0 + k0s;     // er row of offset-index 0 (always >= 0)

    // ---- prologue: stage er offset-indices [0,127] into the ring ----
    {
        const int row = tid >> 1;           // 0..127
        const int g4 = (tid & 1) * 4;       // granules g4..g4+3
        const int e = min(E0 + row, 2047);
        const unsigned short* ep = er16 + (size_t)e * 64;
#pragma unroll
        for (int j = 0; j < 4; ++j) {
            bf16x8 v = load8(ep + (g4 + j) * 8);
            *reinterpret_cast<bf16x8*>(Er_s + row * 64 + (((g4 + j) ^ (row & 7)) * 8)) = v;
        }
    }

    float m = -INFINITY, lsum = 0.f;
    f32x4 acc_o[4];
#pragma unroll
    for (int mf = 0; mf < 4; ++mf) acc_o[mf] = f32x4{0.f, 0.f, 0.f, 0.f};

    // ---- prefetch tile 0 K/V into regs ----
    bf16x8 kpr0, kpr1, vpr0, vpr1, epr0, epr1;
    {
        const unsigned short* krow = qk16 + ((size_t)(k0s + sk) * BATCH + b) * 1024 + 512 + hh * HDIM;
        kpr0 = load8(krow + dg0 * 8);       kpr1 = load8(krow + (dg0 + 4) * 8);
        const unsigned short* vbase = vT16 + (((size_t)bh * 32 + (k0s >> 6)) * 64) * 64;
        vpr0 = load8(vbase + dv0 * 64 + gv * 8);
        vpr1 = load8(vbase + (dv0 + 8) * 64 + gv * 8);
    }

    for (int t = 0; t < ntl; ++t) {
        const int k0 = k0s + t * 64;
        __syncthreads();
        // ---- write prefetched K, V^T (swizzled b128) ----
        *reinterpret_cast<bf16x8*>(K_s + sk * 64 + ((dg0 ^ (sk & 7)) * 8)) = kpr0;
        *reinterpret_cast<bf16x8*>(K_s + sk * 64 + (((dg0 + 4) ^ (sk & 7)) * 8)) = kpr1;
        *reinterpret_cast<bf16x8*>(V_T + dv0 * 64 + ((gv ^ (dv0 & 7)) * 8)) = vpr0;
        *reinterpret_cast<bf16x8*>(V_T + (dv0 + 8) * 64 + ((gv ^ (dv0 & 7)) * 8)) = vpr1;
        // ---- write Er ring half: offset-indices [64t+64, 64t+127] (prefetched iter t-1) ----
        if (t >= 1) {
            const int rb = ((64 * t + 64) & 127) + sk;     // position = oi & 127
            *reinterpret_cast<bf16x8*>(Er_s + rb * 64 + ((dg0 ^ (sk & 7)) * 8)) = epr0;
            *reinterpret_cast<bf16x8*>(Er_s + rb * 64 + (((dg0 + 4) ^ (sk & 7)) * 8)) = epr1;
        }
        // ---- prefetch next tile's K/V and next iter's Er half ----
        if (t + 1 < ntl) {
            const unsigned short* krow = qk16 + ((size_t)(k0 + 64 + sk) * BATCH + b) * 1024 + 512 + hh * HDIM;
            kpr0 = load8(krow + dg0 * 8);       kpr1 = load8(krow + (dg0 + 4) * 8);
            const unsigned short* vbase = vT16 + (((size_t)bh * 32 + ((k0 + 64) >> 6)) * 64) * 64;
            vpr0 = load8(vbase + dv0 * 64 + gv * 8);
            vpr1 = load8(vbase + (dv0 + 8) * 64 + gv * 8);
            // Er for write at iter t+1: oi = 64t + 128 + sk
            const int e = min(E0 + 64 * t + 128 + sk, 2047);
            epr0 = load8(er16 + (size_t)e * 64 + dg0 * 8);
            epr1 = load8(er16 + (size_t)e * 64 + (dg0 + 4) * 8);
        }
        __syncthreads();

        // ---- QK: S^T[k][q] = K x Q ----
        f32x4 sacc[4];
#pragma unroll
        for (int f = 0; f < 4; ++f) {
            const int row = l15 + 16 * f;
            bf16x8 ka0 = *reinterpret_cast<const bf16x8*>(K_s + row * 64 + (((0 + hi) ^ (l15 & 7)) * 8));
            bf16x8 ka1 = *reinterpret_cast<const bf16x8*>(K_s + row * 64 + (((4 + hi) ^ (l15 & 7)) * 8));
            f32x4 z = {0.f, 0.f, 0.f, 0.f};
            z = MFMA16(ka0, qf0, z);
            sacc[f] = MFMA16(ka1, qf1, z);
        }

        // ---- QE in-tile: 5 groups cover E_w cols [0,79] ----
#pragma unroll
        for (int g = 0; g < 5; ++g) {
            const int rg = (48 - 16 * w + 16 * g + 64 * t) & 127;
            const int row = (rg + l15) & 127;              // ring row (wrap fix)
            const unsigned short* eb = Er_s + row * 64;
            bf16x8 a0 = *reinterpret_cast<const bf16x8*>(eb + ((hi ^ (l15 & 7)) * 8));
            bf16x8 a1 = *reinterpret_cast<const bf16x8*>(eb + (((hi + 4) ^ (l15 & 7)) * 8));
            f32x4 qe = {0.f, 0.f, 0.f, 0.f};
            qe = MFMA16(a0, qf0, qe);
            qe = MFMA16(a1, qf1, qe);
            u16x4 ew;
#pragma unroll
            for (int r = 0; r < 4; ++r) ew[r] = f2bf(qe[r]);
            *reinterpret_cast<u16x4*>(ewp + 16 * g + 4 * hi) = ew;
        }
        __builtin_amdgcn_sched_barrier(0);   // pin QE writes before the gather

        // ---- gather QE diagonal + causal mask + online softmax (in-place) ----
        const unsigned short* gwp = ewp + (15 - l15);
        const bool needmask = (k0 + 63 > q0 + 16 * w);     // wave-uniform
        float mt = -INFINITY;
#pragma unroll
        for (int f = 0; f < 4; ++f) {
#pragma unroll
            for (int r = 0; r < 4; ++r) {
                const int kk = 16 * f + 4 * hi + r;
                float sv = sacc[f][r] + bf2f(gwp[kk]);
                if (needmask && (k0 + kk > qg)) sv = -1e9f;
                sacc[f][r] = sv;
                mt = fmaxf(mt, sv);
            }
        }
        mt = fmaxf(mt, __shfl_xor(mt, 16));
        mt = fmaxf(mt, __shfl_xor(mt, 32));
        const float mn = fmaxf(m, mt);
        const float corr = __expf(m - mn);
        float ps = 0.f;
#pragma unroll
        for (int f = 0; f < 4; ++f)
#pragma unroll
            for (int r = 0; r < 4; ++r) {
                const float e = __expf(sacc[f][r] - mn);
                sacc[f][r] = e; ps += e;
            }
        ps += __shfl_xor(ps, 16);
        ps += __shfl_xor(ps, 32);
        lsum = lsum * corr + ps;
        m = mn;

        // ---- pack P to bf16 B-frags ----
        bf16x8 pf0, pf1;
#pragma unroll
        for (int j = 0; j < 8; ++j) {
            pf0[j] = (short)f2bf(sacc[j >> 2][j & 3]);
            pf1[j] = (short)f2bf(sacc[(j >> 2) + 2][j & 3]);
        }

        // ---- rescale + PV: ctx^T = V^T x P (direct b128 A-frags) ----
#pragma unroll
        for (int mf = 0; mf < 4; ++mf) {
            f32x4 a = acc_o[mf];
            a[0] *= corr; a[1] *= corr; a[2] *= corr; a[3] *= corr;
            const unsigned short* vrow = V_T + (l15 + 16 * mf) * 64;
            const int sw = l15 & 7;
            bf16x8 vf0 = *reinterpret_cast<const bf16x8*>(vrow + ((hi ^ sw) * 8));
            bf16x8 vf1 = *reinterpret_cast<const bf16x8*>(vrow + (((4 + hi) ^ sw) * 8));
            a = MFMA16(vf0, pf0, a);
            a = MFMA16(vf1, pf1, a);
            acc_o[mf] = a;
        }
    }

    // ---- epilogue: write un-normalized partials ----
    unsigned short* pa = part16 + ((size_t)pidx * 64 + 16 * w + l15) * 64;
#pragma unroll
    for (int mf = 0; mf < 4; ++mf) {
        u16x4 o;
#pragma unroll
        for (int r = 0; r < 4; ++r) o[r] = f2bf(acc_o[mf][r]);
        *reinterpret_cast<u16x4*>(pa + 16 * mf + 4 * hi) = o;
    }
    if (hi == 0) {
        float* ml = mlbuf + ((size_t)pidx * 64 + 16 * w + l15) * 2;
        ml[0] = m; ml[1] = lsum;
    }
}

// ---------------- combine partials -> ctx16 (up to 4 chunks, online merge) ----------------
// inverse of the heavy-first task mapping:
//   chunk cc of qb: if qb-8cc>=7 -> idx = {0,25,42,51}[cc] + (31-qb)
//                   else          -> idx = 52 + 4*(6-(qb-8cc)) + cc
__global__ __launch_bounds__(256) void attn_combine_kernel(
    const unsigned short* __restrict__ part16, const float* __restrict__ mlbuf,
    unsigned short* __restrict__ ctx16)
{
    const int flat = blockIdx.x * 256 + threadIdx.x;
    const int qi = flat >> 3, dg = flat & 7;
    const int bh = qi >> 11, ql = qi & 2047;
    const int b = bh >> 3, hh = bh & 7;
    const int qb = ql >> 6, rl = ql & 63;

    const int nch = (qb >> 3) + 1;              // 1..4 chunks
    float mr = -1e30f, lr = 0.f;
    float o[8];
#pragma unroll
    for (int j = 0; j < 8; ++j) o[j] = 0.f;

    for (int cc = 0; cc < nch; ++cc) {
        int idx;
        if (qb - 8 * cc >= 7) {
            const int base = (cc == 0) ? 0 : (cc == 1) ? 25 : (cc == 2) ? 42 : 51;
            idx = bh * 80 + base + (31 - qb);
        } else {
            idx = bh * 80 + 52 + 4 * (6 - (qb - 8 * cc)) + cc;
        }
        const float* ml = mlbuf + ((size_t)idx * 64 + rl) * 2;
        const float mc = ml[0], lc = ml[1];
        u16x8 a = *reinterpret_cast<const u16x8*>(part16 + ((size_t)idx * 64 + rl) * 64 + dg * 8);
        const float mn = fmaxf(mr, mc);
        const float w0 = __expf(mr - mn), w1 = __expf(mc - mn);
#pragma unroll
        for (int j = 0; j < 8; ++j) o[j] = o[j] * w0 + bf2f(a[j]) * w1;
        lr = lr * w0 + lc * w1;
        mr = mn;
    }
    const float inv = 1.f / lr;
    u16x8 res;
#pragma unroll
    for (int j = 0; j < 8; ++j) res[j] = f2bf(o[j] * inv);
    *reinterpret_cast<u16x8*>(ctx16 + ((size_t)ql * BATCH + b) * DMODEL + hh * HDIM + dg * 8) = res;
}

// ---------------- LayerNorm (fused residual add), writes f32 + bf16 ----------------
__global__ __launch_bounds__(256) void ln_kernel(
    const float* __restrict__ xin, const float* __restrict__ res,
    const float* __restrict__ gg, const float* __restrict__ bb,
    float* __restrict__ xout, unsigned short* __restrict__ x16out, int has_res)
{
    const int w = threadIdx.x >> 6, lane = threadIdx.x & 63;
    const int row = blockIdx.x * 4 + w;
    const float* xp = xin + (size_t)row * DMODEL + lane * 8;
    f32x4 v0 = *reinterpret_cast<const f32x4*>(xp);
    f32x4 v1 = *reinterpret_cast<const f32x4*>(xp + 4);
    if (has_res) {
        const float* rp = res + (size_t)row * DMODEL + lane * 8;
        v0 += *reinterpret_cast<const f32x4*>(rp);
        v1 += *reinterpret_cast<const f32x4*>(rp + 4);
    }
    float sum = 0.f, ssq = 0.f;
#pragma unroll
    for (int c2 = 0; c2 < 4; ++c2) {
        sum += v0[c2] + v1[c2];
        ssq += v0[c2] * v0[c2] + v1[c2] * v1[c2];
    }
#pragma unroll
    for (int off = 32; off > 0; off >>= 1) {
        sum += __shfl_xor(sum, off);
        ssq += __shfl_xor(ssq, off);
    }
    const float mu = sum * (1.f / 512.f);
    const float var = ssq * (1.f / 512.f) - mu * mu;
    const float rstd = rsqrtf(var + 1e-5f);
    f32x4 g0 = *reinterpret_cast<const f32x4*>(gg + lane * 8);
    f32x4 g1 = *reinterpret_cast<const f32x4*>(gg + lane * 8 + 4);
    f32x4 b0 = *reinterpret_cast<const f32x4*>(bb + lane * 8);
    f32x4 b1 = *reinterpret_cast<const f32x4*>(bb + lane * 8 + 4);
    f32x4 o0, o1;
    u16x8 h;
#pragma unroll
    for (int c2 = 0; c2 < 4; ++c2) {
        o0[c2] = (v0[c2] - mu) * rstd * g0[c2] + b0[c2];
        o1[c2] = (v1[c2] - mu) * rstd * g1[c2] + b1[c2];
        h[c2] = f2bf(o0[c2]); h[4 + c2] = f2bf(o1[c2]);
    }
    float* op = xout + (size_t)row * DMODEL + lane * 8;
    *reinterpret_cast<f32x4*>(op)     = o0;
    *reinterpret_cast<f32x4*>(op + 4) = o1;
    *reinterpret_cast<u16x8*>(x16out + (size_t)row * DMODEL + lane * 8) = h;
}

// ---------------- host launch ----------------
extern "C" void kernel_launch(void* const* d_in, const int* in_sizes, int n_in,
                              void* d_out, int out_size, void* d_ws, size_t ws_size,
                              hipStream_t stream)
{
    const int*   seq  = (const int*)d_in[0];
    const float* emb  = (const float*)d_in[1];
    const float* ipw  = (const float*)d_in[2];
    const float* ipb  = (const float*)d_in[3];
    const float* opw  = (const float*)d_in[4];
    const float* opb  = (const float*)d_in[5];
    const float* er   = (const float*)d_in[6];
    const float* l1w  = (const float*)d_in[7];
    const float* l1b  = (const float*)d_in[8];
    const float* l2w  = (const float*)d_in[9];
    const float* l2b  = (const float*)d_in[10];
    const float* ln1g = (const float*)d_in[11];
    const float* ln1b = (const float*)d_in[12];
    const float* ln2g = (const float*)d_in[13];
    const float* ln2b = (const float*)d_in[14];
    const float* flng = (const float*)d_in[15];
    const float* flnb = (const float*)d_in[16];
    const float* ww   = (const float*)d_in[17];
    const float* wb   = (const float*)d_in[18];
    float* out = (float*)d_out;

    float* xf  = (float*)d_ws;                               // [4096][512] f32
    float* tmp = xf + (size_t)MROWS * DMODEL;                // [4096][512] f32
    unsigned short* x16   = (unsigned short*)(tmp + (size_t)MROWS * DMODEL);  // [4096][512]
    unsigned short* qk16  = x16  + (size_t)MROWS * DMODEL;   // [4096][1024] (h16 aliases)
    unsigned short* ctx16 = qk16 + (size_t)MROWS * 1024;     // [4096][512]
    unsigned short* er16  = ctx16 + (size_t)MROWS * DMODEL;  // [6][2048][64]
    unsigned short* vT16  = er16 + (size_t)LAYERS * S_LEN * HDIM;  // [16][32][64][64]
    unsigned short* w16   = vT16 + (size_t)16 * 32 * 64 * 64;
    unsigned short* h16   = qk16;                            // alias (disjoint lifetime)
    // attention partials overlay tmp+x16 (both dead during attn -> combine):
    unsigned short* part16 = (unsigned short*)tmp;
    float* mlbuf = (float*)(part16 + (size_t)1280 * 64 * 64);

    unsigned short* ipw16 = w16;                             // 6*1536*512
    unsigned short* opw16 = ipw16 + (size_t)LAYERS * 1536 * DMODEL;
    unsigned short* l1w16 = opw16 + (size_t)LAYERS * DMODEL * DMODEL;
    unsigned short* l2w16 = l1w16 + (size_t)LAYERS * 1024 * DMODEL;
    unsigned short* ww16  = l2w16 + (size_t)LAYERS * DMODEL * 1024;

    // ---- weight + er conversion (once per launch) ----
    {
        int n8;
        n8 = LAYERS * 1536 * DMODEL / 8; f2bf_kernel<<<(n8 + 255) / 256, 256, 0, stream>>>(ipw, ipw16, n8);
        n8 = LAYERS * DMODEL * DMODEL / 8; f2bf_kernel<<<(n8 + 255) / 256, 256, 0, stream>>>(opw, opw16, n8);
        n8 = LAYERS * 1024 * DMODEL / 8; f2bf_kernel<<<(n8 + 255) / 256, 256, 0, stream>>>(l1w, l1w16, n8);
        n8 = LAYERS * DMODEL * 1024 / 8; f2bf_kernel<<<(n8 + 255) / 256, 256, 0, stream>>>(l2w, l2w16, n8);
        n8 = 267 * DMODEL / 8;           f2bf_kernel<<<(n8 + 255) / 256, 256, 0, stream>>>(ww, ww16, n8);
        n8 = LAYERS * S_LEN * HDIM / 8;  f2bf_kernel<<<(n8 + 255) / 256, 256, 0, stream>>>(er, er16, n8);
    }

    embed_pe_kernel<<<MROWS, 256, 0, stream>>>(seq, emb, xf, x16);

    for (int i = 0; i < LAYERS; ++i) {
        gemm_mfma_kernel<128><<<dim3(24, 32), 256, 0, stream>>>(
            x16, ipw16 + (size_t)i * 1536 * DMODEL, ipb + (size_t)i * 1536,
            nullptr, qk16, vT16, 1536, DMODEL, 0, 1);
        attn_mfma_kernel<<<dim3(BATCH * NHEAD, 80), 256, 0, stream>>>(
            qk16, vT16, er16 + (size_t)i * S_LEN * HDIM, part16, mlbuf);
        attn_combine_kernel<<<1024, 256, 0, stream>>>(part16, mlbuf, ctx16);
        gemm_mfma_kernel<64><<<dim3(8, 64), 256, 0, stream>>>(
            ctx16, opw16 + (size_t)i * DMODEL * DMODEL, opb + (size_t)i * DMODEL,
            tmp, nullptr, nullptr, DMODEL, DMODEL, 0, 0);
        ln_kernel<<<MROWS / 4, 256, 0, stream>>>(
            xf, tmp, ln1g + (size_t)i * DMODEL, ln1b + (size_t)i * DMODEL, xf, x16, 1);
        gemm_mfma_kernel<128><<<dim3(16, 32), 256, 0, stream>>>(
            x16, l1w16 + (size_t)i * 1024 * DMODEL, l1b + (size_t)i * 1024,
            nullptr, h16, nullptr, 1024, DMODEL, 1, 0);
        gemm_mfma_kernel<64><<<dim3(8, 64), 256, 0, stream>>>(
            h16, l2w16 + (size_t)i * DMODEL * 1024, l2b + (size_t)i * DMODEL,
            tmp, nullptr, nullptr, DMODEL, 1024, 0, 0);
        ln_kernel<<<MROWS / 4, 256, 0, stream>>>(
            xf, tmp, ln2g + (size_t)i * DMODEL, ln2b + (size_t)i * DMODEL, xf, x16, 1);
    }

    ln_kernel<<<MROWS / 4, 256, 0, stream>>>(xf, nullptr, flng, flnb, xf, x16, 0);
    gemm_mfma_kernel<64><<<dim3(5, 64), 256, 0, stream>>>(
        x16, ww16, wb, out, nullptr, nullptr, 267, DMODEL, 0, 0);
}